// Round 5
// baseline (235.567 us; speedup 1.0000x reference)
//
#include <hip/hip_runtime.h>

// Derivative1D: y[b, i, c] = x[b, i+1, c] - x[b, i, c]
// x: (B=64, L=16384, C=32) fp32 contiguous; y: (B, L-1, C) fp32.
// Flattened per batch: out[r] = x[r + C] - x[r], r in [0, (L-1)*C).
//
// V4: persistent grid-stride kernel with explicit 1-deep prefetch pipeline.
//     Evidence (V3 rocprof): one-shot structure = 80us, 2.5 TB/s, 31% peak,
//     VALUBusy 10%, occupancy 54% -> latency-bound, not BW-bound.
//     2048 blocks (8/CU), 16 iters/thread; issue iter i+1 loads before
//     computing iter i, so compiler emits counted vmcnt waits and keeps
//     2 load-pairs/thread permanently in flight.

typedef float f32x4 __attribute__((ext_vector_type(4)));

constexpr int B = 64;
constexpr int L = 16384;
constexpr int C = 32;
constexpr int PER_BATCH    = (L - 1) * C;      // 524256 floats per batch (out)
constexpr int PER_BATCH_V4 = PER_BATCH / 4;    // 131064 float4 per batch (exact)
constexpr int IN_PER_BATCH = L * C;            // 524288 floats per batch (in)

constexpr int BLOCK  = 256;
constexpr int GX     = 32;                     // blocks per batch -> 32*64 = 2048 blocks total
constexpr int STRIDE = GX * BLOCK;             // 8192 float4 per sweep
constexpr int ITERS  = (PER_BATCH_V4 + STRIDE - 1) / STRIDE;   // 16

__global__ __launch_bounds__(BLOCK) void deriv1d_kernel(const float* __restrict__ x,
                                                        float* __restrict__ out) {
    const int b = blockIdx.y;
    const float* xb = x   + (size_t)b * IN_PER_BATCH;
    float*       ob = out + (size_t)b * PER_BATCH;

    int i = blockIdx.x * BLOCK + threadIdx.x;  // float4 index within batch

    // Prologue: load iteration 0.
    f32x4 a, n;
    bool ok = i < PER_BATCH_V4;
    if (ok) {
        const float* p = xb + (size_t)i * 4;
        a = *reinterpret_cast<const f32x4*>(p);
        n = *reinterpret_cast<const f32x4*>(p + C);
    }

#pragma unroll
    for (int it = 0; it < ITERS; ++it) {
        // Prefetch next iteration first (independent of current compute).
        const int inext = i + STRIDE;
        f32x4 a2, n2;
        const bool ok2 = (it + 1 < ITERS) && (inext < PER_BATCH_V4);
        if (ok2) {
            const float* p = xb + (size_t)inext * 4;
            a2 = *reinterpret_cast<const f32x4*>(p);
            n2 = *reinterpret_cast<const f32x4*>(p + C);
        }
        // Compute + store current (waits only on current's loads; next stays in flight).
        if (ok) {
            *reinterpret_cast<f32x4*>(ob + (size_t)i * 4) = n - a;
        }
        i = inext; ok = ok2; a = a2; n = n2;
    }
}

extern "C" void kernel_launch(void* const* d_in, const int* in_sizes, int n_in,
                              void* d_out, int out_size, void* d_ws, size_t ws_size,
                              hipStream_t stream) {
    const float* x = (const float*)d_in[0];
    float* out = (float*)d_out;

    dim3 grid(GX, B);       // 2048 blocks = 8 per CU
    dim3 block(BLOCK);
    deriv1d_kernel<<<grid, block, 0, stream>>>(x, out);
}

// Round 7
// 217.786 us; speedup vs baseline: 1.0816x; 1.0816x over previous
//
#include <hip/hip_runtime.h>

// Derivative1D: y[b, i, c] = x[b, i+1, c] - x[b, i, c]
// x: (B=64, L=16384, C=32) fp32 contiguous; y: (B, L-1, C) fp32.
// Flattened per batch: out[r] = x[r + C] - x[r], r in [0, (L-1)*C).
//
// V5: V0's structure (1 float4/thread, 2D grid, best so far at 222.5us) +
//     in-register dedupe of the second read stream:
//       C floats = 8 float4 = 8 lanes, so n[lane] = a[lane+8] within the wave.
//     Global read instructions per wave: 2 -> 1.125 (only lanes 56-63 load
//     their neighbor float4 directly). Evidence: V3/V4 rocprof showed the
//     kernel at 2.5 TB/s with HBM 69% idle, occupancy/MLP ruled out ->
//     suspect duplicated read-request path (L1 re-serves 87.5%-overlapping
//     lines for the n-stream).
// NOTE: no early-return -- all 64 lanes must be active for the shuffle;
//       tail is handled by predicating the halo load and the store.

typedef float f32x4 __attribute__((ext_vector_type(4)));

constexpr int B = 64;
constexpr int L = 16384;
constexpr int C = 32;
constexpr int PER_BATCH    = (L - 1) * C;      // 524256 floats per batch (out)
constexpr int PER_BATCH_V4 = PER_BATCH / 4;    // 131064 float4 per batch (exact)
constexpr int IN_PER_BATCH = L * C;            // 524288 floats per batch (in)

__global__ __launch_bounds__(256) void deriv1d_kernel(const float* __restrict__ x,
                                                      float* __restrict__ out) {
    const int r4   = blockIdx.x * 256 + threadIdx.x;   // float4 index within batch
    const int b    = blockIdx.y;
    const int lane = threadIdx.x & 63;

    const float* xb = x   + (size_t)b * IN_PER_BATCH;
    float*       ob = out + (size_t)b * PER_BATCH;

    // a-load is safe for ALL threads in the grid: max r4 = 131071 ->
    // floats [524284, 524288) which is exactly the end of the batch.
    const f32x4 a = *reinterpret_cast<const f32x4*>(xb + (size_t)r4 * 4);

    // n = a from lane+8 (same wave) for lanes 0..55.
    f32x4 n;
    n.x = __shfl_down(a.x, 8);
    n.y = __shfl_down(a.y, 8);
    n.z = __shfl_down(a.z, 8);
    n.w = __shfl_down(a.w, 8);

    // Lanes 56..63: neighbor is in the next wave's chunk -> direct halo load.
    // Predicated on r4 < PER_BATCH_V4 so the tail never reads past the batch.
    if (lane >= 56 && r4 < PER_BATCH_V4) {
        n = *reinterpret_cast<const f32x4*>(xb + (size_t)r4 * 4 + C);
    }

    if (r4 < PER_BATCH_V4) {
        *reinterpret_cast<f32x4*>(ob + (size_t)r4 * 4) = n - a;
    }
}

extern "C" void kernel_launch(void* const* d_in, const int* in_sizes, int n_in,
                              void* d_out, int out_size, void* d_ws, size_t ws_size,
                              hipStream_t stream) {
    const float* x = (const float*)d_in[0];
    float* out = (float*)d_out;

    // 131064 float4 per batch -> 512 blocks of 256 (tail predicated, not returned)
    dim3 grid((PER_BATCH_V4 + 255) / 256, B);
    dim3 block(256);
    deriv1d_kernel<<<grid, block, 0, stream>>>(x, out);
}